// Round 5
// baseline (159.866 us; speedup 1.0000x reference)
//
#include <hip/hip_runtime.h>

typedef __attribute__((ext_vector_type(8))) short short8;
typedef __attribute__((ext_vector_type(4))) short short4v;
typedef __attribute__((ext_vector_type(4))) float f32x4;

__device__ __forceinline__ short f2bf(float f) {
  unsigned u = __builtin_bit_cast(unsigned, f);
  u = u + 0x7fffu + ((u >> 16) & 1u);
  return (short)(u >> 16);
}
__device__ __forceinline__ float bf2f(short s) {
  unsigned u = ((unsigned)(unsigned short)s) << 16;
  return __builtin_bit_cast(float, u);
}

// ------------------------------------------------ fused: gn_stats + weight cast
__global__ __launch_bounds__(256) void pre_kernel(
    const float* __restrict__ x, float2* __restrict__ part,
    const float* __restrict__ wq, const float* __restrict__ wk,
    const float* __restrict__ wv, const float* __restrict__ wp,
    short* __restrict__ wout) {
  const int blk = blockIdx.x, t = threadIdx.x;
  if (blk < 1024) {
    const float* base = x + (long)blk * 8192;
    float s = 0.f, ss = 0.f;
#pragma unroll
    for (int j = 0; j < 8; ++j) {
      float4 v = ((const float4*)base)[t + j * 256];
      s  += v.x + v.y + v.z + v.w;
      ss += v.x * v.x + v.y * v.y + v.z * v.z + v.w * v.w;
    }
    for (int o = 32; o > 0; o >>= 1) { s += __shfl_xor(s, o, 64); ss += __shfl_xor(ss, o, 64); }
    __shared__ float rs[4], rss[4];
    if ((t & 63) == 0) { rs[t >> 6] = s; rss[t >> 6] = ss; }
    __syncthreads();
    if (t == 0) {
      part[blk] = make_float2(rs[0] + rs[1] + rs[2] + rs[3],
                              rss[0] + rss[1] + rss[2] + rss[3]);
    }
  } else {
    int i = (blk - 1024) * 256 + t;
    wout[i]          = f2bf(wq[i]);
    wout[262144 + i] = f2bf(wk[i]);
    wout[524288 + i] = f2bf(wv[i]);
    wout[786432 + i] = f2bf(wp[i]);
  }
}

// ------------------------------------------------ GN pass 2: normalize+transpose
#define TP 133
__global__ __launch_bounds__(256) void gn_norm_t(
    const float* __restrict__ x, const float2* __restrict__ part,
    const float* __restrict__ gamma, const float* __restrict__ beta,
    short* __restrict__ xnt) {
  const int blk = blockIdx.x;
  const int nc = blk & 7, g = (blk >> 3) & 7, b = blk >> 6;
  const int t = threadIdx.x;
  float s = 0.f, ss = 0.f;
#pragma unroll
  for (int j = 0; j < 8; ++j) {
    float2 p = part[(b * 8 + g) * 8 + j];
    s += p.x; ss += p.y;
  }
  const float mean = s * (1.f / 65536.f);
  const float var  = ss * (1.f / 65536.f) - mean * mean;
  const float rstd = rsqrtf(var + 1e-5f);

  const float* base = x + (long)(b * 512 + g * 64) * 1024 + nc * 128;
  __shared__ float tile[64][TP];
  const int row = t >> 2, c4 = t & 3;
#pragma unroll
  for (int j = 0; j < 8; ++j) {
    float4 v = *(const float4*)(base + (long)row * 1024 + (c4 + j * 4) * 4);
    *(float4*)&tile[row][(c4 + j * 4) * 4] = v;
  }
  const int cl4 = (t & 15) * 4;
  float ga[4], be[4];
#pragma unroll
  for (int j = 0; j < 4; ++j) {
    float gm = gamma[g * 64 + cl4 + j];
    ga[j] = gm * rstd;
    be[j] = beta[g * 64 + cl4 + j] - mean * ga[j];
  }
  __syncthreads();
  short* outb = xnt + (long)b * 524288 + (long)(nc * 128) * 512 + g * 64 + cl4;
#pragma unroll
  for (int it = 0; it < 8; ++it) {
    const int tok = (t >> 4) + it * 16;
    short4v o;
    o.x = f2bf(tile[cl4 + 0][tok] * ga[0] + be[0]);
    o.y = f2bf(tile[cl4 + 1][tok] * ga[1] + be[1]);
    o.z = f2bf(tile[cl4 + 2][tok] * ga[2] + be[2]);
    o.w = f2bf(tile[cl4 + 3][tok] * ga[3] + be[3]);
    *(short4v*)(outb + (long)tok * 512) = o;
  }
}

// ------------------------------------------------ row softmax, 1 wave per row
__global__ __launch_bounds__(256) void softmax_kernel(short* __restrict__ S) {
  const int t = threadIdx.x, lane = t & 63;
  const long row = (long)blockIdx.x * 4 + (t >> 6);
  short* p = S + row * 1024;
  short8 a = *(short8*)(p + lane * 8);
  short8 b = *(short8*)(p + 512 + lane * 8);
  float va[8], vb[8];
  float m = -1e30f;
#pragma unroll
  for (int j = 0; j < 8; ++j) {
    va[j] = bf2f(a[j]); vb[j] = bf2f(b[j]);
    m = fmaxf(m, fmaxf(va[j], vb[j]));
  }
#pragma unroll
  for (int o = 32; o > 0; o >>= 1) m = fmaxf(m, __shfl_xor(m, o, 64));
  float s = 0.f;
#pragma unroll
  for (int j = 0; j < 8; ++j) {
    va[j] = __expf(va[j] - m); vb[j] = __expf(vb[j] - m);
    s += va[j] + vb[j];
  }
#pragma unroll
  for (int o = 32; o > 0; o >>= 1) s += __shfl_xor(s, o, 64);
  const float inv = 1.f / s;
#pragma unroll
  for (int j = 0; j < 8; ++j) { a[j] = f2bf(va[j] * inv); b[j] = f2bf(vb[j] * inv); }
  *(short8*)(p + lane * 8) = a;
  *(short8*)(p + 512 + lane * 8) = b;
}

// ------------------------------------------------ GEMM core, 3-buf pipeline
// C[M,N] = A[M,K] * Bt[N,K]^T, bf16, lda=ldb=K. 128x128 tile, BK=32, 4 waves.
// Depth-2 prefetch, counted vmcnt(4), raw s_barrier (no vmcnt(0) drain).
// LDS layout per matrix tile (4096 shorts): "super-row" sr = 2 rows (64
// shorts = 128B); 16B granule pg = lg ^ (sr&7) where lg = (row&1)*4 + (k>>3).
__device__ __forceinline__ int swz32(int a, int g) {  // row a, k-granule g(0..3)
  const int sr = a >> 1;
  const int pg = (((a & 1) << 2) | g) ^ (sr & 7);
  return sr * 64 + pg * 8;
}

__device__ __forceinline__ void stage2(
    const short* __restrict__ Ab, const short* __restrict__ Bb,
    short* base, const long* aoff, const long* boff, const int* ldst, long k0) {
#pragma unroll
  for (int it = 0; it < 2; ++it) {
    __builtin_amdgcn_global_load_lds(
        (const __attribute__((address_space(1))) void*)(Ab + aoff[it] + k0),
        (__attribute__((address_space(3))) void*)(base + ldst[it]), 16, 0, 0);
    __builtin_amdgcn_global_load_lds(
        (const __attribute__((address_space(1))) void*)(Bb + boff[it] + k0),
        (__attribute__((address_space(3))) void*)(base + 4096 + ldst[it]), 16, 0, 0);
  }
}

__device__ __forceinline__ void gemm_core_p3(
    const short* __restrict__ Ab, const short* __restrict__ Bb,
    short* lds, f32x4 (&acc)[4][4], int m0, int n0, int K, int tid) {
  const int lane = tid & 63, w = tid >> 6;
  const int wm = (w >> 1) * 64, wn = (w & 1) * 64;
  long aoff[2], boff[2];
  int ldst[2];
#pragma unroll
  for (int it = 0; it < 2; ++it) {
    const int ci = w * 2 + it;
    const int sr = ci * 8 + (lane >> 3);
    const int lg = (lane & 7) ^ (sr & 7);       // logical granule for this lane
    const int row = sr * 2 + (lg >> 2);
    const int kcol = (lg & 3) * 8;
    aoff[it] = (long)(m0 + row) * K + kcol;
    boff[it] = (long)(n0 + row) * K + kcol;
    ldst[it] = ci * 512 + lane * 8;             // linear LDS dest
  }
  const int NT = K >> 5;
  stage2(Ab, Bb, lds, aoff, boff, ldst, 0);
  stage2(Ab, Bb, lds + 8192, aoff, boff, ldst, 32);

  int cur = 0, sb = 2;
  const int g = lane >> 4, ar = lane & 15;
  for (int t = 0; t < NT; ++t) {
    if (t < NT - 1) { asm volatile("s_waitcnt vmcnt(4)" ::: "memory"); }
    else            { asm volatile("s_waitcnt vmcnt(0)" ::: "memory"); }
    __builtin_amdgcn_sched_barrier(0);
    __builtin_amdgcn_s_barrier();
    __builtin_amdgcn_sched_barrier(0);
    const short* buf = lds + cur * 8192;
    short8 af[4], bfv[4];
#pragma unroll
    for (int i = 0; i < 4; ++i) {
      af[i]  = *(const short8*)(buf + swz32(wm + i * 16 + ar, g));
      bfv[i] = *(const short8*)(buf + 4096 + swz32(wn + i * 16 + ar, g));
    }
    __builtin_amdgcn_s_setprio(1);
#pragma unroll
    for (int i = 0; i < 4; ++i)
#pragma unroll
      for (int j = 0; j < 4; ++j)
        acc[i][j] = __builtin_amdgcn_mfma_f32_16x16x32_bf16(af[i], bfv[j], acc[i][j], 0, 0, 0);
    __builtin_amdgcn_s_setprio(0);
    if (t + 2 < NT) stage2(Ab, Bb, lds + sb * 8192, aoff, boff, ldst, (long)(t + 2) * 32);
    cur = (cur == 2) ? 0 : cur + 1;
    sb  = (sb == 2) ? 0 : sb + 1;
  }
}

// ------------------------------------------------ fused QKV projection GEMM
// y 0..7: A=W_qk (stacked [1024,512]), B=xnt  -> q_t/k_t [tok][ch] (packed 8B)
// y 8..11: A=xnt (tokens), B=wv              -> vbf [ch][tok] (packed 8B)
__global__ __launch_bounds__(256, 3) void qkv_gemm(
    const short* __restrict__ W, const short* __restrict__ xnt,
    short* __restrict__ q_t, short* __restrict__ k_t, short* __restrict__ vbf,
    const float* __restrict__ bq, const float* __restrict__ bk,
    const float* __restrict__ bv) {
  __shared__ short lds[24576];
  const int b = blockIdx.z, y = blockIdx.y, xg = blockIdx.x;
  const int tid = threadIdx.x, lane = tid & 63, w = tid >> 6;
  const int wm = (w >> 1) * 64, wn = (w & 1) * 64;
  const short* xb = xnt + (long)b * 524288;
  f32x4 acc[4][4] = {};

  if (y < 8) {
    const int m0 = y * 128, n0 = xg * 128;  // m: stacked q/k channel, n: token
    gemm_core_p3(W, xb, lds, acc, m0, n0, 512, tid);
    const int which = y >> 2;
    short* C = (which ? k_t : q_t) + (long)b * 524288;
    const float* bias = which ? bk : bq;
    const int mb = m0 - which * 512 + wm + (lane >> 4) * 4;
    const int nb = n0 + wn + (lane & 15);
#pragma unroll
    for (int i = 0; i < 4; ++i) {
      int m = mb + i * 16;
      float b0 = bias[m], b1 = bias[m + 1], b2 = bias[m + 2], b3 = bias[m + 3];
#pragma unroll
      for (int j = 0; j < 4; ++j) {
        int n = nb + j * 16;
        short4v o;
        o.x = f2bf(acc[i][j][0] + b0);
        o.y = f2bf(acc[i][j][1] + b1);
        o.z = f2bf(acc[i][j][2] + b2);
        o.w = f2bf(acc[i][j][3] + b3);
        *(short4v*)(C + (long)n * 512 + m) = o;  // [tok][ch]
      }
    }
  } else {
    const int t = (y - 8) * 8 + xg;
    const int m0 = (t >> 2) * 128;  // tokens
    const int n0 = (t & 3) * 128;   // v channels
    gemm_core_p3(xb, W + 524288, lds, acc, m0, n0, 512, tid);
    short* C = vbf + (long)b * 524288;  // [ch][tok], stride 1024
    const int mb = m0 + wm + (lane >> 4) * 4;
    const int nb = n0 + wn + (lane & 15);
#pragma unroll
    for (int i = 0; i < 4; ++i) {
      int m = mb + i * 16;
#pragma unroll
      for (int j = 0; j < 4; ++j) {
        int n = nb + j * 16;
        float bi = bv[n];
        short4v o;
        o.x = f2bf(acc[i][j][0] + bi);
        o.y = f2bf(acc[i][j][1] + bi);
        o.z = f2bf(acc[i][j][2] + bi);
        o.w = f2bf(acc[i][j][3] + bi);
        *(short4v*)(C + (long)n * 1024 + m) = o;  // [ch][tok]
      }
    }
  }
}

// ------------------------------------------------ generic GEMM (S / PV / out)
enum { EPI_TRANS_BF16 = 0, EPI_RES_F32 = 2 };

template <int EPI>
__global__ __launch_bounds__(256, 3) void gemm_bt(
    const short* __restrict__ A, const short* __restrict__ Bt,
    void* __restrict__ Cv, const float* __restrict__ bias,
    const float* __restrict__ resid, float scale,
    int M, int N, int K, long aStr, long bStr, long cStr, long rStr) {
  __shared__ short lds[24576];
  const int b = blockIdx.z;
  const short* Ab = A + (long)b * aStr;
  const short* Bb = Bt + (long)b * bStr;
  const int m0 = blockIdx.y * 128, n0 = blockIdx.x * 128;
  const int tid = threadIdx.x, lane = tid & 63, w = tid >> 6;
  f32x4 acc[4][4] = {};
  gemm_core_p3(Ab, Bb, lds, acc, m0, n0, K, tid);

  const int wm = (w >> 1) * 64, wn = (w & 1) * 64;
  const int mb = m0 + wm + (lane >> 4) * 4;
  const int nb = n0 + wn + (lane & 15);
  if constexpr (EPI == EPI_TRANS_BF16) {
    // write C^T: [n][m], row stride M, packed 8B
    short* C = (short*)Cv + (long)b * cStr;
#pragma unroll
    for (int i = 0; i < 4; ++i) {
      int m = mb + i * 16;
      float b0 = 0.f, b1 = 0.f, b2 = 0.f, b3 = 0.f;
      if (bias) { b0 = bias[m]; b1 = bias[m + 1]; b2 = bias[m + 2]; b3 = bias[m + 3]; }
#pragma unroll
      for (int j = 0; j < 4; ++j) {
        int n = nb + j * 16;
        short4v o;
        o.x = f2bf(acc[i][j][0] * scale + b0);
        o.y = f2bf(acc[i][j][1] * scale + b1);
        o.z = f2bf(acc[i][j][2] * scale + b2);
        o.w = f2bf(acc[i][j][3] * scale + b3);
        *(short4v*)(C + (long)n * M + m) = o;
      }
    }
  } else {  // EPI_RES_F32: C[m][n] f32 + bias[m] + resid
    float* C = (float*)Cv + (long)b * cStr;
    const float* R = resid + (long)b * rStr;
#pragma unroll
    for (int i = 0; i < 4; ++i) {
#pragma unroll
      for (int r = 0; r < 4; ++r) {
        int m = mb + i * 16 + r;
        float bi = bias[m];
#pragma unroll
        for (int j = 0; j < 4; ++j) {
          int n = nb + j * 16;
          C[(long)m * N + n] = acc[i][j][r] + bi + R[(long)m * N + n];
        }
      }
    }
  }
}

// ---------------------------------------------------------------- launch
extern "C" void kernel_launch(void* const* d_in, const int* in_sizes, int n_in,
                              void* d_out, int out_size, void* d_ws, size_t ws_size,
                              hipStream_t stream) {
  const float* x     = (const float*)d_in[0];
  const float* gamma = (const float*)d_in[1];
  const float* beta  = (const float*)d_in[2];
  const float* wq    = (const float*)d_in[3];
  const float* bq    = (const float*)d_in[4];
  const float* wk    = (const float*)d_in[5];
  const float* bk    = (const float*)d_in[6];
  const float* wv    = (const float*)d_in[7];
  const float* bv    = (const float*)d_in[8];
  const float* wp    = (const float*)d_in[9];
  const float* bp    = (const float*)d_in[10];

  char* ws = (char*)d_ws;
  short* wbf = (short*)ws;                       // [wq;wk;wv;wp] bf16, 2 MB
  short* xnt = (short*)(ws + 2097152l);          // [B,N,C] bf16, 16 MB
  short* q_t = (short*)(ws + 18874368l);         // [B,tok,ch]
  short* k_t = (short*)(ws + 35651584l);         // [B,tok,ch]
  short* vbf = (short*)(ws + 52428800l);         // [B,ch,tok]
  short* Sbf = (short*)(ws + 69206016l);         // [B,N,N] bf16, 33.5 MB
  short* h_t = xnt;                              // alias (xn dead after qkv)
  float2* gnpart = (float2*)Sbf;                 // 8 KB, dead before S written

  pre_kernel<<<2048, 256, 0, stream>>>(x, gnpart, wq, wk, wv, wp, wbf);
  gn_norm_t<<<1024, 256, 0, stream>>>(x, gnpart, gamma, beta, xnt);

  qkv_gemm<<<dim3(8, 12, 16), 256, 0, stream>>>(
      wbf, xnt, q_t, k_t, vbf, bq, bk, bv);

  const float iscale = 0.044194173824159216f;  // 1/sqrt(512)
  // S = (k_t . q_t^T)^T * scale  -> S[i][j] packed stores
  gemm_bt<EPI_TRANS_BF16><<<dim3(8, 8, 16), 256, 0, stream>>>(
      k_t, q_t, Sbf, nullptr, nullptr, iscale, 1024, 1024, 512, 524288, 524288, 1048576, 0);
  softmax_kernel<<<4096, 256, 0, stream>>>(Sbf);
  // h_t[tok][ch] = (v[ch][:] . S^T)^T  (A=vbf M=512ch, Bt=Sbf N=1024tok, K=1024)
  gemm_bt<EPI_TRANS_BF16><<<dim3(8, 4, 16), 256, 0, stream>>>(
      vbf, Sbf, h_t, nullptr, nullptr, 1.f, 512, 1024, 1024, 524288, 1048576, 524288, 0);
  // out = wp . h^T + bp + x   (NORM f32, [ch][tok])
  gemm_bt<EPI_RES_F32><<<dim3(8, 4, 16), 256, 0, stream>>>(
      wbf + 786432, h_t, d_out, bp, x, 1.f, 512, 1024, 512, 0, 524288, 524288, 524288);
}

// Round 6
// 138.797 us; speedup vs baseline: 1.1518x; 1.1518x over previous
//
#include <hip/hip_runtime.h>

typedef __attribute__((ext_vector_type(8))) short short8;
typedef __attribute__((ext_vector_type(4))) short short4v;
typedef __attribute__((ext_vector_type(4))) float f32x4;

__device__ __forceinline__ short f2bf(float f) {
  unsigned u = __builtin_bit_cast(unsigned, f);
  u = u + 0x7fffu + ((u >> 16) & 1u);
  return (short)(u >> 16);
}
__device__ __forceinline__ float bf2f(short s) {
  unsigned u = ((unsigned)(unsigned short)s) << 16;
  return __builtin_bit_cast(float, u);
}

// ---------------- fused: gn_stats + weight cast + lsum zero
// blk 0..1023: GN partials; 1024..2047: wcast; 2048..2051: zero lsum (16K f32).
__global__ __launch_bounds__(256) void pre_kernel(
    const float* __restrict__ x, float2* __restrict__ part,
    const float* __restrict__ wq, const float* __restrict__ wk,
    const float* __restrict__ wv, const float* __restrict__ wp,
    short* __restrict__ wout, float* __restrict__ lz) {
  const int blk = blockIdx.x, t = threadIdx.x;
  if (blk < 1024) {
    const float* base = x + (long)blk * 8192;
    float s = 0.f, ss = 0.f;
#pragma unroll
    for (int j = 0; j < 8; ++j) {
      float4 v = ((const float4*)base)[t + j * 256];
      s  += v.x + v.y + v.z + v.w;
      ss += v.x * v.x + v.y * v.y + v.z * v.z + v.w * v.w;
    }
    for (int o = 32; o > 0; o >>= 1) { s += __shfl_xor(s, o, 64); ss += __shfl_xor(ss, o, 64); }
    __shared__ float rs[4], rss[4];
    if ((t & 63) == 0) { rs[t >> 6] = s; rss[t >> 6] = ss; }
    __syncthreads();
    if (t == 0) {
      part[blk] = make_float2(rs[0] + rs[1] + rs[2] + rs[3],
                              rss[0] + rss[1] + rss[2] + rss[3]);
    }
  } else if (blk < 2048) {
    int i = (blk - 1024) * 256 + t;
    wout[i]          = f2bf(wq[i]);
    wout[262144 + i] = f2bf(wk[i]);
    wout[524288 + i] = f2bf(wv[i]);
    wout[786432 + i] = f2bf(wp[i]);
  } else {
    float4* p = (float4*)lz;
    const int base = (blk - 2048) * 1024 + t * 4;
#pragma unroll
    for (int k = 0; k < 4; ++k) p[base + k] = make_float4(0.f, 0.f, 0.f, 0.f);
  }
}

// ---------------- GN pass 2: normalize + transpose to xnt[B,N,C]
#define TP 133
__global__ __launch_bounds__(256) void gn_norm_t(
    const float* __restrict__ x, const float2* __restrict__ part,
    const float* __restrict__ gamma, const float* __restrict__ beta,
    short* __restrict__ xnt) {
  const int blk = blockIdx.x;
  const int nc = blk & 7, g = (blk >> 3) & 7, b = blk >> 6;
  const int t = threadIdx.x;
  float s = 0.f, ss = 0.f;
#pragma unroll
  for (int j = 0; j < 8; ++j) {
    float2 p = part[(b * 8 + g) * 8 + j];
    s += p.x; ss += p.y;
  }
  const float mean = s * (1.f / 65536.f);
  const float var  = ss * (1.f / 65536.f) - mean * mean;
  const float rstd = rsqrtf(var + 1e-5f);

  const float* base = x + (long)(b * 512 + g * 64) * 1024 + nc * 128;
  __shared__ float tile[64][TP];
  const int row = t >> 2, c4 = t & 3;
#pragma unroll
  for (int j = 0; j < 8; ++j) {
    float4 v = *(const float4*)(base + (long)row * 1024 + (c4 + j * 4) * 4);
    *(float4*)&tile[row][(c4 + j * 4) * 4] = v;
  }
  const int cl4 = (t & 15) * 4;
  float ga[4], be[4];
#pragma unroll
  for (int j = 0; j < 4; ++j) {
    float gm = gamma[g * 64 + cl4 + j];
    ga[j] = gm * rstd;
    be[j] = beta[g * 64 + cl4 + j] - mean * ga[j];
  }
  __syncthreads();
  short* outb = xnt + (long)b * 524288 + (long)(nc * 128) * 512 + g * 64 + cl4;
#pragma unroll
  for (int it = 0; it < 8; ++it) {
    const int tok = (t >> 4) + it * 16;
    short4v o;
    o.x = f2bf(tile[cl4 + 0][tok] * ga[0] + be[0]);
    o.y = f2bf(tile[cl4 + 1][tok] * ga[1] + be[1]);
    o.z = f2bf(tile[cl4 + 2][tok] * ga[2] + be[2]);
    o.w = f2bf(tile[cl4 + 3][tok] * ga[3] + be[3]);
    *(short4v*)(outb + (long)tok * 512) = o;
  }
}

// ---------------- GEMM core (round-3 proven: single-buffer, 2-barrier)
// C[M,N] = A[M,K] * Bt[N,K]^T, bf16 row-major, 128x128 tile, BK=64, 4 waves.
#define BM 128
#define BK 64
enum { EPI_TRANS_BF16 = 0, EPI_NORM_BF16 = 1, EPI_RES_F32 = 2, EPI_EXP_T = 3, EPI_PV = 4 };

__device__ __forceinline__ int swz_idx(int row, int k) {
  return row * 64 + ((((k >> 3) ^ row) & 7) << 3) + (k & 7);
}

__device__ __forceinline__ void gemm_core(
    const short* __restrict__ Ab, const short* __restrict__ Bb,
    short* lds, f32x4 (&acc)[4][4], int m0, int n0, int K, int tid) {
  const int lane = tid & 63, w = tid >> 6;
  const int wm = (w >> 1) * 64, wn = (w & 1) * 64;
  const int rowst = w * 32 + (lane >> 3);
  for (int k0 = 0; k0 < K; k0 += BK) {
    __syncthreads();
#pragma unroll
    for (int it = 0; it < 4; ++it) {
      int ci = w * 4 + it;
      int row = rowst + it * 8;
      int slot = (lane & 7) ^ (row & 7);
      const short* ga = Ab + (long)(m0 + row) * K + k0 + slot * 8;
      __builtin_amdgcn_global_load_lds(
          (const __attribute__((address_space(1))) void*)ga,
          (__attribute__((address_space(3))) void*)(lds + ci * 512), 16, 0, 0);
      const short* gb = Bb + (long)(n0 + row) * K + k0 + slot * 8;
      __builtin_amdgcn_global_load_lds(
          (const __attribute__((address_space(1))) void*)gb,
          (__attribute__((address_space(3))) void*)(lds + 8192 + ci * 512), 16, 0, 0);
    }
    __syncthreads();
#pragma unroll
    for (int kk = 0; kk < 2; ++kk) {
      short8 af[4], bf[4];
      const int kf = kk * 32 + (lane >> 4) * 8;
#pragma unroll
      for (int i = 0; i < 4; ++i) {
        af[i] = *(const short8*)(lds + swz_idx(wm + i * 16 + (lane & 15), kf));
        bf[i] = *(const short8*)(lds + 8192 + swz_idx(wn + i * 16 + (lane & 15), kf));
      }
#pragma unroll
      for (int i = 0; i < 4; ++i)
#pragma unroll
        for (int j = 0; j < 4; ++j)
          acc[i][j] = __builtin_amdgcn_mfma_f32_16x16x32_bf16(af[i], bf[j], acc[i][j], 0, 0, 0);
    }
  }
}

// ---------------- fused QKV projection GEMM (round-3 proven layout)
// W stacked [wq;wk;wv] = [1536,512]. grid (8, 12, 16).
__global__ __launch_bounds__(256, 3) void qkv_gemm(
    const short* __restrict__ W, const short* __restrict__ xnt,
    short* __restrict__ q_t, short* __restrict__ k_t, short* __restrict__ vbf,
    const float* __restrict__ bq, const float* __restrict__ bk,
    const float* __restrict__ bv) {
  __shared__ short lds[2 * BM * BK];
  const int b = blockIdx.z, y = blockIdx.y;
  const int which = y >> 2;
  const int m0 = y * BM;
  const int mloc0 = m0 - which * 512;
  const int n0 = blockIdx.x * BM;
  const short* Bb = xnt + (long)b * 524288;
  const int tid = threadIdx.x, lane = tid & 63, w = tid >> 6;
  f32x4 acc[4][4] = {};
  gemm_core(W, Bb, lds, acc, m0, n0, 512, tid);

  const int wm = (w >> 1) * 64, wn = (w & 1) * 64;
  const int mb = mloc0 + wm + (lane >> 4) * 4;
  const int nb = n0 + wn + (lane & 15);
  if (which < 2) {
    short* C = (which ? k_t : q_t) + (long)b * 524288;
    const float* bias = which ? bk : bq;
#pragma unroll
    for (int i = 0; i < 4; ++i) {
      int m = mb + i * 16;
      float b0 = bias[m], b1 = bias[m + 1], b2 = bias[m + 2], b3 = bias[m + 3];
#pragma unroll
      for (int j = 0; j < 4; ++j) {
        int n = nb + j * 16;
        short4v o;
        o.x = f2bf(acc[i][j][0] + b0);
        o.y = f2bf(acc[i][j][1] + b1);
        o.z = f2bf(acc[i][j][2] + b2);
        o.w = f2bf(acc[i][j][3] + b3);
        *(short4v*)(C + (long)n * 512 + m) = o;  // [tok][ch]
      }
    }
  } else {
    short* C = vbf + (long)b * 524288;  // [ch][tok]
#pragma unroll
    for (int i = 0; i < 4; ++i) {
#pragma unroll
      for (int r = 0; r < 4; ++r) {
        int m = mb + i * 16 + r;
        float bi = bv[m];
#pragma unroll
        for (int j = 0; j < 4; ++j) {
          int n = nb + j * 16;
          C[(long)m * 1024 + n] = f2bf(acc[i][j][r] + bi);
        }
      }
    }
  }
}

// ---------------- generic GEMM (S-exp / PV / out)
template <int EPI>
__global__ __launch_bounds__(256, 3) void gemm_bt(
    const short* __restrict__ A, const short* __restrict__ Bt,
    void* __restrict__ Cv, const float* __restrict__ bias,
    const float* __restrict__ resid, float scale,
    int M, int N, int K, long aStr, long bStr, long cStr, long rStr,
    float* __restrict__ lsum) {
  __shared__ short lds[2 * BM * BK];
  const int b = blockIdx.z;
  const short* Ab = A + (long)b * aStr;
  const short* Bb = Bt + (long)b * bStr;
  const int m0 = blockIdx.y * BM, n0 = blockIdx.x * BM;
  const int tid = threadIdx.x, lane = tid & 63, w = tid >> 6;
  f32x4 acc[4][4] = {};
  gemm_core(Ab, Bb, lds, acc, m0, n0, K, tid);

  const int wm = (w >> 1) * 64, wn = (w & 1) * 64;
  const int mb = m0 + wm + (lane >> 4) * 4;
  const int nb = n0 + wn + (lane & 15);
  if constexpr (EPI == EPI_EXP_T) {
    // A=keys, Bt=queries. Write P' = exp(S*scale) transposed: C[q*M + key],
    // packed 8B along keys; accumulate per-query row sums into lsum[b][q].
    short* C = (short*)Cv + (long)b * cStr;
    float rowsum[4] = {0.f, 0.f, 0.f, 0.f};
#pragma unroll
    for (int j = 0; j < 4; ++j) {
      int n = nb + j * 16;  // query
#pragma unroll
      for (int i = 0; i < 4; ++i) {
        int m = mb + i * 16;  // key
        float e0 = __expf(acc[i][j][0] * scale);
        float e1 = __expf(acc[i][j][1] * scale);
        float e2 = __expf(acc[i][j][2] * scale);
        float e3 = __expf(acc[i][j][3] * scale);
        rowsum[j] += (e0 + e1) + (e2 + e3);
        short4v o;
        o.x = f2bf(e0); o.y = f2bf(e1); o.z = f2bf(e2); o.w = f2bf(e3);
        *(short4v*)(C + (long)n * M + m) = o;
      }
    }
#pragma unroll
    for (int j = 0; j < 4; ++j) {
      rowsum[j] += __shfl_xor(rowsum[j], 16, 64);
      rowsum[j] += __shfl_xor(rowsum[j], 32, 64);
    }
    if (lane < 16) {
#pragma unroll
      for (int j = 0; j < 4; ++j)
        atomicAdd(&lsum[b * 1024 + nb + j * 16], rowsum[j]);
    }
  } else if constexpr (EPI == EPI_PV) {
    // A=P'[q][key], Bt=v[ch][key]. h[q][ch] = acc / lsum[b][q].
    short* C = (short*)Cv + (long)b * cStr;
#pragma unroll
    for (int i = 0; i < 4; ++i) {
#pragma unroll
      for (int r = 0; r < 4; ++r) {
        int m = mb + i * 16 + r;  // query
        float rl = 1.0f / lsum[b * 1024 + m];
#pragma unroll
        for (int j = 0; j < 4; ++j) {
          int n = nb + j * 16;  // channel
          C[(long)m * N + n] = f2bf(acc[i][j][r] * rl);
        }
      }
    }
  } else if constexpr (EPI == EPI_NORM_BF16) {
    short* C = (short*)Cv + (long)b * cStr;
#pragma unroll
    for (int i = 0; i < 4; ++i) {
#pragma unroll
      for (int r = 0; r < 4; ++r) {
        int m = mb + i * 16 + r;
        float bi = bias ? bias[m] : 0.f;
#pragma unroll
        for (int j = 0; j < 4; ++j) {
          int n = nb + j * 16;
          C[(long)m * N + n] = f2bf(acc[i][j][r] * scale + bi);
        }
      }
    }
  } else {  // EPI_RES_F32
    float* C = (float*)Cv + (long)b * cStr;
    const float* R = resid + (long)b * rStr;
#pragma unroll
    for (int i = 0; i < 4; ++i) {
#pragma unroll
      for (int r = 0; r < 4; ++r) {
        int m = mb + i * 16 + r;
        float bi = bias[m];
#pragma unroll
        for (int j = 0; j < 4; ++j) {
          int n = nb + j * 16;
          C[(long)m * N + n] = acc[i][j][r] + bi + R[(long)m * N + n];
        }
      }
    }
  }
}

// ---------------------------------------------------------------- launch
extern "C" void kernel_launch(void* const* d_in, const int* in_sizes, int n_in,
                              void* d_out, int out_size, void* d_ws, size_t ws_size,
                              hipStream_t stream) {
  const float* x     = (const float*)d_in[0];
  const float* gamma = (const float*)d_in[1];
  const float* beta  = (const float*)d_in[2];
  const float* wq    = (const float*)d_in[3];
  const float* bq    = (const float*)d_in[4];
  const float* wk    = (const float*)d_in[5];
  const float* bk    = (const float*)d_in[6];
  const float* wv    = (const float*)d_in[7];
  const float* bv    = (const float*)d_in[8];
  const float* wp    = (const float*)d_in[9];
  const float* bp    = (const float*)d_in[10];

  char* ws = (char*)d_ws;
  short* wbf = (short*)ws;                       // [wq;wk;wv;wp] bf16, 2 MB
  short* xnt = (short*)(ws + 2097152l);          // [B,N,C] bf16, 16 MB
  short* q_t = (short*)(ws + 18874368l);         // [B,tok,ch]
  short* k_t = (short*)(ws + 35651584l);         // [B,tok,ch]
  short* vbf = (short*)(ws + 52428800l);         // [B,ch,tok]
  short* Sbf = (short*)(ws + 69206016l);         // [B,N,N] bf16 (P')
  short* h_t = xnt;                              // alias (xn dead after qkv)
  float2* gnpart = (float2*)Sbf;                 // 8 KB, dead before S written
  float* lsum = (float*)d_out;                   // 64 KB; proj overwrites later

  pre_kernel<<<2052, 256, 0, stream>>>(x, gnpart, wq, wk, wv, wp, wbf, lsum);
  gn_norm_t<<<1024, 256, 0, stream>>>(x, gnpart, gamma, beta, xnt);

  qkv_gemm<<<dim3(8, 12, 16), 256, 0, stream>>>(
      wbf, xnt, q_t, k_t, vbf, bq, bk, bv);

  const float iscale = 0.044194173824159216f;  // 1/sqrt(512)
  // P' = exp((k_t . q_t^T)^T * scale), rowsums -> lsum
  gemm_bt<EPI_EXP_T><<<dim3(8, 8, 16), 256, 0, stream>>>(
      k_t, q_t, Sbf, nullptr, nullptr, iscale, 1024, 1024, 512,
      524288, 524288, 1048576, 0, lsum);
  // h_t[q][ch] = (P' . v^T) / lsum[q]
  gemm_bt<EPI_PV><<<dim3(4, 8, 16), 256, 0, stream>>>(
      Sbf, vbf, h_t, nullptr, nullptr, 1.f, 1024, 512, 1024,
      1048576, 524288, 524288, 0, lsum);
  // out = wp . h^T + bp + x
  gemm_bt<EPI_RES_F32><<<dim3(8, 4, 16), 256, 0, stream>>>(
      wbf + 786432, h_t, d_out, bp, x, 1.f, 512, 1024, 512,
      0, 524288, 524288, 524288, nullptr);
}